// Round 10
// baseline (119.792 us; speedup 1.0000x reference)
//
#include <hip/hip_runtime.h>
#include <stdint.h>

#define B 128
#define F 8192
#define H 8192
#define S 4
#define K 32
#define L 3
#define C 100

#define NBLK 256
#define NTHR 512

// ---------------------------------------------------------------------------
// Planar-PAIR activation layout: plane (l, wp) is contiguous:
//   base u32 = (l*2 + wp) * 2 * H;  entry h = {word 2wp, word 2wp+1} uint2.
// Word w covers batches w*32..w*32+31, bit = b & 31. xPP analogous.
// Layers are independent per word-pair, BUT the final phase reads both
// word-pairs' planes -> ALL in-kernel barriers are FULL-GRID.
// Barrier state is zeroed by the INIT DISPATCH (dispatch-boundary ordering)
// -> no in-kernel init handshake, no stale-state race class at all.
// ---------------------------------------------------------------------------

__device__ __forceinline__ int load_threshold(const int* p) {
    int v = *p;
    if (v >= (1 << 23)) v = (int)__int_as_float(v);
    return v;
}

// carry-save add of one 0/1-mask word into a 5-deep bit-sliced counter
__device__ __forceinline__ void cs5(uint32_t* a, uint32_t v) {
#pragma unroll
    for (int i = 0; i < 5; ++i) { const uint32_t t = a[i]; a[i] = t ^ v; v = t & v; }
}

// sum own 5-bit sliced counter with lane^32 partner's -> 6-bit result in y
__device__ __forceinline__ void pair_sum5(const uint32_t* x, uint32_t* y) {
    uint32_t c = 0;
#pragma unroll
    for (int i = 0; i < 5; ++i) {
        const uint32_t p = (uint32_t)__shfl_xor((int)x[i], 32);
        const uint32_t s = x[i] ^ p;
        y[i] = s ^ c;
        c = (x[i] & p) | (s & c);
    }
    y[5] = c;
}

// fired = (2P >= A + thr), bit-sliced over 7 bits; A,P are 6-deep (<=32)
__device__ __forceinline__ uint32_t fired_cmp(const uint32_t* A, const uint32_t* P, int thr) {
    uint32_t Y[7];
    uint32_t c = 0;
#pragma unroll
    for (int i = 0; i < 7; ++i) {
        const uint32_t ai = (i < 6) ? A[i] : 0u;
        const uint32_t bm = ((thr >> i) & 1) ? 0xFFFFFFFFu : 0u;
        const uint32_t t  = ai ^ bm;
        Y[i] = t ^ c;
        c = (ai & bm) | (t & c);
    }
    uint32_t bw = 0;
#pragma unroll
    for (int i = 0; i < 7; ++i) {
        const uint32_t xx = (i >= 1) ? P[i - 1] : 0u;
        const uint32_t d  = xx ^ Y[i];
        bw = ((~xx) & Y[i]) | ((~d) & bw);
    }
    return ~bw;
}

// async global->LDS, 16 B per lane
#define GLDS16(gp, lp)                                                \
    __builtin_amdgcn_global_load_lds(                                 \
        (const __attribute__((address_space(1))) uint32_t*)(gp),      \
        (__attribute__((address_space(3))) uint32_t*)(lp), 16, 0, 0)

#define AG_LOAD(p)                                                          \
    __hip_atomic_load((p), __ATOMIC_RELAXED, __HIP_MEMORY_SCOPE_AGENT)
#define AG_STORE(p, v)                                                      \
    __hip_atomic_store((p), (v), __ATOMIC_RELAXED, __HIP_MEMORY_SCOPE_AGENT)

// ---------------------------------------------------------------------------
// FULL-GRID two-level pure-atomic barrier (256 blocks, 8 groups x 32).
// bar layout (u32): group counters [g*32] g=0..7, root [256], release
// flags [512 + g*32]. All state PRE-ZEROED by the init dispatch.
// Payload coherence: sc1 (LLC) stores + vmcnt(0) drain before arrival.
// Guards break (fail loud as wrong answer) rather than hang.
// ---------------------------------------------------------------------------
__device__ __forceinline__ void grid_barrier(uint32_t* bar, uint32_t ep,
                                             int tid, int gidx) {
    asm volatile("s_waitcnt vmcnt(0)" ::: "memory");   // payload stores at LLC
    __syncthreads();
    if (tid == 0) {
        const uint32_t t = __hip_atomic_fetch_add(&bar[gidx * 32], 1u,
                               __ATOMIC_RELAXED, __HIP_MEMORY_SCOPE_AGENT) + 1u;
        if (t == ep * 32u) {
            const uint32_t r = __hip_atomic_fetch_add(&bar[256], 1u,
                               __ATOMIC_RELAXED, __HIP_MEMORY_SCOPE_AGENT) + 1u;
            if (r == ep * 8u) {
#pragma unroll
                for (int g = 0; g < 8; ++g) AG_STORE(&bar[512 + g * 32], ep);
            }
        }
        int guard = 0;
        while (AG_LOAD(&bar[512 + gidx * 32]) < ep) {
            __builtin_amdgcn_s_sleep(2);
            if (++guard > (1 << 18)) break;            // fail loud, don't hang
        }
    }
    __syncthreads();
    asm volatile("" ::: "memory");
}

// ---------------------------------------------------------------------------
// One layer, wp-split: block = 64 h-rows x 1 word-pair x 4 segments.
// 512 threads = 8 waves: wave (s = ww&3, rh = ww>>2); lane (h5 = lane&31,
// kh = lane>>5; K split 16/16, combined via shfl_xor(32)).
//  - idx/signs register loads issued at top, overlapping the GLDS staging.
//  - tab: one 64 KiB plane via global_load_lds dwordx4 (8 rounds).
//  - uint2 gathers feed carry-save counters for both words; bit-sliced
//    compare; OR across segments via fbuf; sc1 plane store (payload).
// ---------------------------------------------------------------------------
__device__ __forceinline__ void layer_phase(
        const uint32_t* __restrict__ prevPlane,  // u32*, 2*H (one wp plane)
        const int* __restrict__ idx,             // (S,H,K)
        const float* __restrict__ signs,         // (S,H,K)
        uint32_t* __restrict__ outPlane,         // u32*, 2*H (one wp plane)
        const int thr, const int hg, const int tid,
        uint2* tab, uint32_t* fbuf) {
    const int lane = tid & 63;
    const int ww   = tid >> 6;
    const int s    = ww & 3;
    const int rh   = ww >> 2;
    const int kh   = lane >> 5;
    const int h5   = lane & 31;
    const int h    = hg * 64 + rh * 32 + h5;

    // ---- issue idx/sign register loads (overlap the GLDS staging) ----
    const size_t gb = ((size_t)s * H + h) * K + kh * 16;
    const int4   i0 = *(const int4*)(idx + gb);
    const int4   i1 = *(const int4*)(idx + gb + 4);
    const int4   i2 = *(const int4*)(idx + gb + 8);
    const int4   i3 = *(const int4*)(idx + gb + 12);
    const float4 s0 = *(const float4*)(signs + gb);
    const float4 s1 = *(const float4*)(signs + gb + 4);
    const float4 s2 = *(const float4*)(signs + gb + 8);
    const float4 s3 = *(const float4*)(signs + gb + 12);

    // ---- stage tab: 64 KiB plane, async direct-to-LDS ----
    {
        uint32_t* lbase = (uint32_t*)tab;
#pragma unroll
        for (int i = 0; i < 8; ++i) {
            const int o = (i * 512 + tid) * 4;      // u32 index, 16 B/lane
            GLDS16(prevPlane + o, lbase + o);
        }
    }
    __syncthreads();   // drains vmcnt (GLDS + reg loads)

    const uint32_t iv[16] = {
        (uint32_t)i0.x, (uint32_t)i0.y, (uint32_t)i0.z, (uint32_t)i0.w,
        (uint32_t)i1.x, (uint32_t)i1.y, (uint32_t)i1.z, (uint32_t)i1.w,
        (uint32_t)i2.x, (uint32_t)i2.y, (uint32_t)i2.z, (uint32_t)i2.w,
        (uint32_t)i3.x, (uint32_t)i3.y, (uint32_t)i3.z, (uint32_t)i3.w };
    const uint32_t pm[16] = {   // ~0 if sign positive
        ~(uint32_t)(__float_as_int(s0.x) >> 31), ~(uint32_t)(__float_as_int(s0.y) >> 31),
        ~(uint32_t)(__float_as_int(s0.z) >> 31), ~(uint32_t)(__float_as_int(s0.w) >> 31),
        ~(uint32_t)(__float_as_int(s1.x) >> 31), ~(uint32_t)(__float_as_int(s1.y) >> 31),
        ~(uint32_t)(__float_as_int(s1.z) >> 31), ~(uint32_t)(__float_as_int(s1.w) >> 31),
        ~(uint32_t)(__float_as_int(s2.x) >> 31), ~(uint32_t)(__float_as_int(s2.y) >> 31),
        ~(uint32_t)(__float_as_int(s2.z) >> 31), ~(uint32_t)(__float_as_int(s2.w) >> 31),
        ~(uint32_t)(__float_as_int(s3.x) >> 31), ~(uint32_t)(__float_as_int(s3.y) >> 31),
        ~(uint32_t)(__float_as_int(s3.z) >> 31), ~(uint32_t)(__float_as_int(s3.w) >> 31) };

    // ---- gather + bit-sliced accumulate (2 words per gather) ----
    uint32_t A0[5] = {0,0,0,0,0}, P0[5] = {0,0,0,0,0};
    uint32_t A1[5] = {0,0,0,0,0}, P1[5] = {0,0,0,0,0};
#pragma unroll
    for (int c8 = 0; c8 < 2; ++c8) {
        uint2 g[8];
#pragma unroll
        for (int j = 0; j < 8; ++j) g[j] = tab[iv[c8 * 8 + j]];
#pragma unroll
        for (int j = 0; j < 8; ++j) {
            const uint32_t pmv = pm[c8 * 8 + j];
            cs5(A0, g[j].x);
            cs5(P0, g[j].x & pmv);
            cs5(A1, g[j].y);
            cs5(P1, g[j].y & pmv);
        }
    }

    // ---- combine k halves (lane^32) -> 6-bit counters ----
    uint32_t A0f[6], P0f[6], A1f[6], P1f[6];
    pair_sum5(A0, A0f);
    pair_sum5(P0, P0f);
    pair_sum5(A1, A1f);
    pair_sum5(P1, P1f);

    const uint32_t f0 = fired_cmp(A0f, P0f, thr);   // word 2wp
    const uint32_t f1 = fired_cmp(A1f, P1f, thr);   // word 2wp+1

    if (kh == 0) {
        fbuf[((s * 2 + rh) * 32 + h5) * 2 + 0] = f0;
        fbuf[((s * 2 + rh) * 32 + h5) * 2 + 1] = f1;
    }
    __syncthreads();

    // ---- OR across 4 segments, write 128 consecutive u32 (sc1 payload) ----
    if (tid < 128) {
        const int rr   = tid >> 6;           // rh
        const int hh   = (tid >> 1) & 31;    // h5
        const int comp = tid & 1;
        uint32_t v = 0;
#pragma unroll
        for (int s2 = 0; s2 < 4; ++s2)
            v |= fbuf[((s2 * 2 + rr) * 32 + hh) * 2 + comp];
        AG_STORE(&outPlane[(size_t)(hg * 64 + rr * 32 + hh) * 2 + comp], v);
    }
}

// ---------------------------------------------------------------------------
// Init kernel (normal dispatch): zero out + ALL barrier state, pack x -> xPP
// planes. 256 blocks x 128 threads (thread = b), 32 f per block. The
// dispatch boundary makes xPP/out/bar coherent & ordered for the fused
// kernel — no in-kernel handshake needed.
// ---------------------------------------------------------------------------
__global__ __launch_bounds__(128) void init_pack_kernel(
        const float* __restrict__ x, uint2* __restrict__ xPP,
        float* __restrict__ out, uint32_t* __restrict__ bar) {
    const int zi = blockIdx.x * 128 + threadIdx.x;
    if (zi < B * C) out[zi] = 0.0f;
    if (blockIdx.x < 8) bar[blockIdx.x * 128 + threadIdx.x] = 0u;  // 1024 u32

    const int b  = threadIdx.x;          // 0..127
    const int wv = threadIdx.x >> 6;     // word pair (0,1)
    const int f0 = blockIdx.x * 32;
    const float4* xr = (const float4*)(x + (size_t)b * F + f0);
    for (int j = 0; j < 8; ++j) {
        const float4 v = xr[j];
        const uint64_t m0 = __ballot(v.x > 0.5f);
        const uint64_t m1 = __ballot(v.y > 0.5f);
        const uint64_t m2 = __ballot(v.z > 0.5f);
        const uint64_t m3 = __ballot(v.w > 0.5f);
        if ((threadIdx.x & 63) == 0) {
            const int f = f0 + 4 * j;
            uint4* dst = (uint4*)(xPP + (size_t)wv * F + f);
            dst[0] = make_uint4((uint32_t)m0, (uint32_t)(m0 >> 32),
                                (uint32_t)m1, (uint32_t)(m1 >> 32));
            dst[1] = make_uint4((uint32_t)m2, (uint32_t)(m2 >> 32),
                                (uint32_t)m3, (uint32_t)(m3 >> 32));
        }
    }
}

// ---------------------------------------------------------------------------
// FUSED kernel, NORMAL launch: 256 blocks x 512 threads, 66 KiB LDS ->
// 2 blocks/CU capacity (co-residency robust even at half the device).
// Block = (hg = bid>>1, wp = bid&1); barriers FULL-GRID, state pre-zeroed
// by init dispatch. L1 | bar1 | L2 | bar2 | L3 [mv01 prefetch] | bar3 |
// [mv2] final.
// ---------------------------------------------------------------------------
__global__ __launch_bounds__(512, 4) void fused_kernel(
        const uint32_t* __restrict__ xPP,      // [2][F] uint2 planes, as u32*
        const int* __restrict__ idx0, const float* __restrict__ signs0,
        const int* __restrict__ idxH, const float* __restrict__ signsH,
        const float* __restrict__ wout, const int* __restrict__ thrp,
        uint32_t* __restrict__ actPP, float* __restrict__ out,
        uint32_t* __restrict__ bar) {
    __shared__ uint2    tab[H];                  // 64 KiB (one wp plane)
    __shared__ uint32_t fbuf[4 * 2 * 32 * 2];    // 2 KiB

    const int tid = threadIdx.x;
    const int bid = blockIdx.x;
    const int wp  = bid & 1;
    const int hg  = bid >> 1;                    // 0..127 (64 h-rows each)
    const int gidx = bid & 7;                    // 32 blocks/group (full grid)
    const int thr = load_threshold(thrp);

    const uint32_t* xPlane = xPP + (size_t)wp * 2 * F;
    uint32_t* pl0 = actPP + (size_t)(0 * 2 + wp) * 2 * H;
    uint32_t* pl1 = actPP + (size_t)(1 * 2 + wp) * 2 * H;
    uint32_t* pl2 = actPP + (size_t)(2 * 2 + wp) * 2 * H;
    const int*   idx2   = idxH;
    const float* signs2 = signsH;
    const int*   idx3   = idxH + (size_t)S * H * K;
    const float* signs3 = signsH + (size_t)S * H * K;

    layer_phase(xPlane, idx0, signs0, pl0, thr, hg, tid, tab, fbuf);
    grid_barrier(bar, 1, tid, gidx);

    layer_phase(pl0, idx2, signs2, pl1, thr, hg, tid, tab, fbuf);
    grid_barrier(bar, 2, tid, gidx);

    layer_phase(pl1, idx3, signs3, pl2, thr, hg, tid, tab, fbuf);

    // final-phase geometry
    const int lane = tid & 63;
    const int gw   = bid * 8 + (tid >> 6);
    const int fb   = gw >> 4;                    // batch b
    const int hc   = gw & 15;                    // h-chunk (512 h)
    const int w32  = fb >> 5;
    const int fwp  = w32 >> 1;
    const int comp = w32 & 1;
    const int bit  = fb & 31;

    // mv[0]/mv[1]: planes grid-complete since bar1/bar2 -> issue BEFORE bar3;
    // their LLC latency overlaps the barrier arrival spread. (16 VGPRs live
    // across one barrier call only - no cross-layer liveness, no spill.)
    uint32_t mv[L][8];
#pragma unroll
    for (int l = 0; l < 2; ++l) {
        const uint32_t* aT = actPP + (size_t)(l * 2 + fwp) * 2 * H + comp;
#pragma unroll
        for (int r = 0; r < 8; ++r)
            mv[l][r] = AG_LOAD(&aT[(size_t)(hc * 512 + r * 64 + lane) * 2]);
    }
    grid_barrier(bar, 3, tid, gidx);

    // mv[2] (needs bar3); its latency hides under the l=0/l=1 walks below
    {
        const uint32_t* aT = actPP + (size_t)(2 * 2 + fwp) * 2 * H + comp;
#pragma unroll
        for (int r = 0; r < 8; ++r)
            mv[2][r] = AG_LOAD(&aT[(size_t)(hc * 512 + r * 64 + lane) * 2]);
    }

    // ---- final: wave = (b, hc); batch-of-4 bit-walk, named scalars only ----
    {
        float acc0 = 0.0f, acc1 = 0.0f;
        const int c1 = 64 + lane;
        const bool c1v = (c1 < C);

#pragma unroll
        for (int l = 0; l < L; ++l) {
            const float* wl = wout + (size_t)l * H * C;
#pragma unroll
            for (int r = 0; r < 8; ++r) {
                const int hbase = hc * 512 + r * 64;
                uint64_t hm = __ballot((mv[l][r] >> bit) & 1u);
                while (hm) {
                    // __ffsll(0)-1 == -1, and hm &= hm-1 is a no-op at 0:
                    // slot extraction needs no conditionals.
                    const int sa = __ffsll((unsigned long long)hm) - 1; hm &= hm - 1;
                    const int sb = __ffsll((unsigned long long)hm) - 1; hm &= hm - 1;
                    const int sc = __ffsll((unsigned long long)hm) - 1; hm &= hm - 1;
                    const int sd = __ffsll((unsigned long long)hm) - 1; hm &= hm - 1;
                    float a0, a1 = 0.0f, b0 = 0.0f, b1 = 0.0f;
                    float c0 = 0.0f, c1f = 0.0f, d0 = 0.0f, d1 = 0.0f;
                    {   // sa is always valid inside the while
                        const float* w = wl + (size_t)(hbase + sa) * C;
                        a0 = w[lane];
                        if (c1v) a1 = w[c1];
                    }
                    if (sb >= 0) {
                        const float* w = wl + (size_t)(hbase + sb) * C;
                        b0 = w[lane];
                        if (c1v) b1 = w[c1];
                    }
                    if (sc >= 0) {
                        const float* w = wl + (size_t)(hbase + sc) * C;
                        c0 = w[lane];
                        if (c1v) c1f = w[c1];
                    }
                    if (sd >= 0) {
                        const float* w = wl + (size_t)(hbase + sd) * C;
                        d0 = w[lane];
                        if (c1v) d1 = w[c1];
                    }
                    acc0 += (a0 + b0) + (c0 + d0);
                    acc1 += (a1 + b1) + (c1f + d1);
                }
            }
        }
        atomicAdd(&out[fb * C + lane], acc0);
        if (c1v) atomicAdd(&out[fb * C + c1], acc1);
    }
}

// ---------------------------------------------------------------------------
extern "C" void kernel_launch(void* const* d_in, const int* in_sizes, int n_in,
                              void* d_out, int out_size, void* d_ws, size_t ws_size,
                              hipStream_t stream) {
    const float* x      = (const float*)d_in[0];   // (B,F)
    const float* signs0 = (const float*)d_in[1];   // (S,H,K)
    const float* signsH = (const float*)d_in[2];   // (L-1,S,H,K)
    const float* wout   = (const float*)d_in[3];   // (L,H,C)
    const int*   idx0   = (const int*)d_in[4];     // (S,H,K)
    const int*   idxH   = (const int*)d_in[5];     // (L-1,S,H,K)
    const int*   thr    = (const int*)d_in[6];     // scalar
    float* out = (float*)d_out;                    // (B,C)

    // Workspace: xPP [2][F] uint2 (128 KiB), actPP [L][2][H] uint2 (384 KiB),
    // barrier state (1024 u32, init-zeroed)
    uint32_t* xPP   = (uint32_t*)d_ws;
    uint32_t* actPP = xPP + (size_t)4 * F;
    uint32_t* bar   = actPP + (size_t)12 * H;
    uint2*    xPP2  = (uint2*)d_ws;

    init_pack_kernel<<<F / 32, 128, 0, stream>>>(x, xPP2, out, bar);
    fused_kernel<<<NBLK, NTHR, 0, stream>>>(xPP, idx0, signs0, idxH, signsH,
                                            wout, thr, actPP, out, bar);
}

// Round 11
// 119.395 us; speedup vs baseline: 1.0033x; 1.0033x over previous
//
#include <hip/hip_runtime.h>
#include <stdint.h>

#define B 128
#define F 8192
#define H 8192
#define S 4
#define K 32
#define L 3
#define C 100

#define NBLK 256
#define NTHR 512

// ---------------------------------------------------------------------------
// Planar-PAIR activation layout: plane (l, wp) is contiguous:
//   base u32 = (l*2 + wp) * 2 * H;  entry h = {word 2wp, word 2wp+1} uint2.
// Word w covers batches w*32..w*32+31, bit = b & 31. xPP analogous.
// Layers are independent per word-pair, BUT the final phase reads both
// word-pairs' planes -> ALL in-kernel barriers are FULL-GRID.
// Barrier state is zeroed by the INIT DISPATCH (dispatch-boundary ordering)
// -> no in-kernel init handshake, no stale-state race class at all.
// ---------------------------------------------------------------------------

__device__ __forceinline__ int load_threshold(const int* p) {
    int v = *p;
    if (v >= (1 << 23)) v = (int)__int_as_float(v);
    return v;
}

// carry-save add of one 0/1-mask word into a 5-deep bit-sliced counter
__device__ __forceinline__ void cs5(uint32_t* a, uint32_t v) {
#pragma unroll
    for (int i = 0; i < 5; ++i) { const uint32_t t = a[i]; a[i] = t ^ v; v = t & v; }
}

// sum own 5-bit sliced counter with lane^32 partner's -> 6-bit result in y
__device__ __forceinline__ void pair_sum5(const uint32_t* x, uint32_t* y) {
    uint32_t c = 0;
#pragma unroll
    for (int i = 0; i < 5; ++i) {
        const uint32_t p = (uint32_t)__shfl_xor((int)x[i], 32);
        const uint32_t s = x[i] ^ p;
        y[i] = s ^ c;
        c = (x[i] & p) | (s & c);
    }
    y[5] = c;
}

// fired = (2P >= A + thr), bit-sliced over 7 bits; A,P are 6-deep (<=32)
__device__ __forceinline__ uint32_t fired_cmp(const uint32_t* A, const uint32_t* P, int thr) {
    uint32_t Y[7];
    uint32_t c = 0;
#pragma unroll
    for (int i = 0; i < 7; ++i) {
        const uint32_t ai = (i < 6) ? A[i] : 0u;
        const uint32_t bm = ((thr >> i) & 1) ? 0xFFFFFFFFu : 0u;
        const uint32_t t  = ai ^ bm;
        Y[i] = t ^ c;
        c = (ai & bm) | (t & c);
    }
    uint32_t bw = 0;
#pragma unroll
    for (int i = 0; i < 7; ++i) {
        const uint32_t xx = (i >= 1) ? P[i - 1] : 0u;
        const uint32_t d  = xx ^ Y[i];
        bw = ((~xx) & Y[i]) | ((~d) & bw);
    }
    return ~bw;
}

// async global->LDS, 16 B per lane
#define GLDS16(gp, lp)                                                \
    __builtin_amdgcn_global_load_lds(                                 \
        (const __attribute__((address_space(1))) uint32_t*)(gp),      \
        (__attribute__((address_space(3))) uint32_t*)(lp), 16, 0, 0)

#define AG_LOAD(p)                                                          \
    __hip_atomic_load((p), __ATOMIC_RELAXED, __HIP_MEMORY_SCOPE_AGENT)
#define AG_STORE(p, v)                                                      \
    __hip_atomic_store((p), (v), __ATOMIC_RELAXED, __HIP_MEMORY_SCOPE_AGENT)

// ---------------------------------------------------------------------------
// FULL-GRID two-level pure-atomic barrier (256 blocks, 8 groups x 32).
// bar layout (u32): group counters [g*32] g=0..7, root [256], release
// flags [512 + g*32]. All state PRE-ZEROED by the init dispatch.
// Payload coherence: sc1 (LLC) stores + vmcnt(0) drain before arrival.
// NOTE: the vmcnt(0) drain also completes any PREFETCH loads the caller
// issued just before the barrier — their HBM latency lands in the barrier
// arrival window (waiting-for-slowest time) instead of after release.
// Guards break (fail loud as wrong answer) rather than hang.
// ---------------------------------------------------------------------------
__device__ __forceinline__ void grid_barrier(uint32_t* bar, uint32_t ep,
                                             int tid, int gidx) {
    asm volatile("s_waitcnt vmcnt(0)" ::: "memory");   // payload stores at LLC
    __syncthreads();
    if (tid == 0) {
        const uint32_t t = __hip_atomic_fetch_add(&bar[gidx * 32], 1u,
                               __ATOMIC_RELAXED, __HIP_MEMORY_SCOPE_AGENT) + 1u;
        if (t == ep * 32u) {
            const uint32_t r = __hip_atomic_fetch_add(&bar[256], 1u,
                               __ATOMIC_RELAXED, __HIP_MEMORY_SCOPE_AGENT) + 1u;
            if (r == ep * 8u) {
#pragma unroll
                for (int g = 0; g < 8; ++g) AG_STORE(&bar[512 + g * 32], ep);
            }
        }
        int guard = 0;
        while (AG_LOAD(&bar[512 + gidx * 32]) < ep) {
            __builtin_amdgcn_s_sleep(2);
            if (++guard > (1 << 18)) break;            // fail loud, don't hang
        }
    }
    __syncthreads();
    asm volatile("" ::: "memory");
}

// idx/sign registers for one layer (8 dwordx4 loads, coalesced 128B/wave)
struct ISRegs { int4 i0, i1, i2, i3; float4 s0, s1, s2, s3; };

__device__ __forceinline__ ISRegs load_is(const int* __restrict__ idx,
                                          const float* __restrict__ signs,
                                          size_t gb) {
    ISRegs r;
    r.i0 = *(const int4*)(idx + gb);
    r.i1 = *(const int4*)(idx + gb + 4);
    r.i2 = *(const int4*)(idx + gb + 8);
    r.i3 = *(const int4*)(idx + gb + 12);
    r.s0 = *(const float4*)(signs + gb);
    r.s1 = *(const float4*)(signs + gb + 4);
    r.s2 = *(const float4*)(signs + gb + 8);
    r.s3 = *(const float4*)(signs + gb + 12);
    return r;
}

// ---------------------------------------------------------------------------
// One layer, wp-split: block = 64 h-rows x 1 word-pair x 4 segments.
// 512 threads = 8 waves: wave (s = ww&3, rh = ww>>2); lane (h5 = lane&31,
// kh = lane>>5; K split 16/16, combined via shfl_xor(32)).
//  - idx/signs arrive as PRE-LOADED REGISTERS (issued before the previous
//    barrier; its vmcnt(0) drain completed them during the arrival window).
//  - tab: one 64 KiB plane via global_load_lds dwordx4 (8 rounds).
//  - uint2 gathers feed carry-save counters for both words; bit-sliced
//    compare; OR across segments via fbuf; sc1 plane store (payload).
// ---------------------------------------------------------------------------
__device__ __forceinline__ void layer_phase(
        const uint32_t* __restrict__ prevPlane,  // u32*, 2*H (one wp plane)
        const ISRegs isr,
        uint32_t* __restrict__ outPlane,         // u32*, 2*H (one wp plane)
        const int thr, const int hg, const int tid,
        uint2* tab, uint32_t* fbuf) {
    const int lane = tid & 63;
    const int ww   = tid >> 6;
    const int s    = ww & 3;
    const int rh   = ww >> 2;
    const int kh   = lane >> 5;
    const int h5   = lane & 31;

    // ---- stage tab: 64 KiB plane, async direct-to-LDS ----
    {
        uint32_t* lbase = (uint32_t*)tab;
#pragma unroll
        for (int i = 0; i < 8; ++i) {
            const int o = (i * 512 + tid) * 4;      // u32 index, 16 B/lane
            GLDS16(prevPlane + o, lbase + o);
        }
    }
    __syncthreads();   // drains vmcnt (GLDS16 staging)

    const uint32_t iv[16] = {
        (uint32_t)isr.i0.x, (uint32_t)isr.i0.y, (uint32_t)isr.i0.z, (uint32_t)isr.i0.w,
        (uint32_t)isr.i1.x, (uint32_t)isr.i1.y, (uint32_t)isr.i1.z, (uint32_t)isr.i1.w,
        (uint32_t)isr.i2.x, (uint32_t)isr.i2.y, (uint32_t)isr.i2.z, (uint32_t)isr.i2.w,
        (uint32_t)isr.i3.x, (uint32_t)isr.i3.y, (uint32_t)isr.i3.z, (uint32_t)isr.i3.w };
    const uint32_t pm[16] = {   // ~0 if sign positive
        ~(uint32_t)(__float_as_int(isr.s0.x) >> 31), ~(uint32_t)(__float_as_int(isr.s0.y) >> 31),
        ~(uint32_t)(__float_as_int(isr.s0.z) >> 31), ~(uint32_t)(__float_as_int(isr.s0.w) >> 31),
        ~(uint32_t)(__float_as_int(isr.s1.x) >> 31), ~(uint32_t)(__float_as_int(isr.s1.y) >> 31),
        ~(uint32_t)(__float_as_int(isr.s1.z) >> 31), ~(uint32_t)(__float_as_int(isr.s1.w) >> 31),
        ~(uint32_t)(__float_as_int(isr.s2.x) >> 31), ~(uint32_t)(__float_as_int(isr.s2.y) >> 31),
        ~(uint32_t)(__float_as_int(isr.s2.z) >> 31), ~(uint32_t)(__float_as_int(isr.s2.w) >> 31),
        ~(uint32_t)(__float_as_int(isr.s3.x) >> 31), ~(uint32_t)(__float_as_int(isr.s3.y) >> 31),
        ~(uint32_t)(__float_as_int(isr.s3.z) >> 31), ~(uint32_t)(__float_as_int(isr.s3.w) >> 31) };

    // ---- gather + bit-sliced accumulate (2 words per gather) ----
    uint32_t A0[5] = {0,0,0,0,0}, P0[5] = {0,0,0,0,0};
    uint32_t A1[5] = {0,0,0,0,0}, P1[5] = {0,0,0,0,0};
#pragma unroll
    for (int c8 = 0; c8 < 2; ++c8) {
        uint2 g[8];
#pragma unroll
        for (int j = 0; j < 8; ++j) g[j] = tab[iv[c8 * 8 + j]];
#pragma unroll
        for (int j = 0; j < 8; ++j) {
            const uint32_t pmv = pm[c8 * 8 + j];
            cs5(A0, g[j].x);
            cs5(P0, g[j].x & pmv);
            cs5(A1, g[j].y);
            cs5(P1, g[j].y & pmv);
        }
    }

    // ---- combine k halves (lane^32) -> 6-bit counters ----
    uint32_t A0f[6], P0f[6], A1f[6], P1f[6];
    pair_sum5(A0, A0f);
    pair_sum5(P0, P0f);
    pair_sum5(A1, A1f);
    pair_sum5(P1, P1f);

    const uint32_t f0 = fired_cmp(A0f, P0f, thr);   // word 2wp
    const uint32_t f1 = fired_cmp(A1f, P1f, thr);   // word 2wp+1

    if (kh == 0) {
        fbuf[((s * 2 + rh) * 32 + h5) * 2 + 0] = f0;
        fbuf[((s * 2 + rh) * 32 + h5) * 2 + 1] = f1;
    }
    __syncthreads();

    // ---- OR across 4 segments, write 128 consecutive u32 (sc1 payload) ----
    if (tid < 128) {
        const int rr   = tid >> 6;           // rh
        const int hh   = (tid >> 1) & 31;    // h5
        const int comp = tid & 1;
        uint32_t v = 0;
#pragma unroll
        for (int s2 = 0; s2 < 4; ++s2)
            v |= fbuf[((s2 * 2 + rr) * 32 + hh) * 2 + comp];
        AG_STORE(&outPlane[(size_t)(hg * 64 + rr * 32 + hh) * 2 + comp], v);
    }
}

// ---------------------------------------------------------------------------
// Init kernel (normal dispatch): zero out + ALL barrier state, pack x -> xPP
// planes. 256 blocks x 128 threads (thread = b), 32 f per block. The
// dispatch boundary makes xPP/out/bar coherent & ordered for the fused
// kernel — no in-kernel handshake needed.
// ---------------------------------------------------------------------------
__global__ __launch_bounds__(128) void init_pack_kernel(
        const float* __restrict__ x, uint2* __restrict__ xPP,
        float* __restrict__ out, uint32_t* __restrict__ bar) {
    const int zi = blockIdx.x * 128 + threadIdx.x;
    if (zi < B * C) out[zi] = 0.0f;
    if (blockIdx.x < 8) bar[blockIdx.x * 128 + threadIdx.x] = 0u;  // 1024 u32

    const int b  = threadIdx.x;          // 0..127
    const int wv = threadIdx.x >> 6;     // word pair (0,1)
    const int f0 = blockIdx.x * 32;
    const float4* xr = (const float4*)(x + (size_t)b * F + f0);
    for (int j = 0; j < 8; ++j) {
        const float4 v = xr[j];
        const uint64_t m0 = __ballot(v.x > 0.5f);
        const uint64_t m1 = __ballot(v.y > 0.5f);
        const uint64_t m2 = __ballot(v.z > 0.5f);
        const uint64_t m3 = __ballot(v.w > 0.5f);
        if ((threadIdx.x & 63) == 0) {
            const int f = f0 + 4 * j;
            uint4* dst = (uint4*)(xPP + (size_t)wv * F + f);
            dst[0] = make_uint4((uint32_t)m0, (uint32_t)(m0 >> 32),
                                (uint32_t)m1, (uint32_t)(m1 >> 32));
            dst[1] = make_uint4((uint32_t)m2, (uint32_t)(m2 >> 32),
                                (uint32_t)m3, (uint32_t)(m3 >> 32));
        }
    }
}

// ---------------------------------------------------------------------------
// FUSED kernel, NORMAL launch: 256 blocks x 512 threads, 66 KiB LDS ->
// 2 blocks/CU capacity (co-residency robust even at half the device).
// Block = (hg = bid>>1, wp = bid&1); barriers FULL-GRID, state pre-zeroed
// by init dispatch. [r1 ld] L1 [r2 ld] | bar1 | L2 [r3 ld] | bar2 | L3
// [mv01 ld] | bar3 | [mv2] final. Every barrier is entered with the next
// phase's global loads issued: the drain completes them during the
// arrival window (free unless this block is the grid's slowest).
// ---------------------------------------------------------------------------
__global__ __launch_bounds__(512, 4) void fused_kernel(
        const uint32_t* __restrict__ xPP,      // [2][F] uint2 planes, as u32*
        const int* __restrict__ idx0, const float* __restrict__ signs0,
        const int* __restrict__ idxH, const float* __restrict__ signsH,
        const float* __restrict__ wout, const int* __restrict__ thrp,
        uint32_t* __restrict__ actPP, float* __restrict__ out,
        uint32_t* __restrict__ bar) {
    __shared__ uint2    tab[H];                  // 64 KiB (one wp plane)
    __shared__ uint32_t fbuf[4 * 2 * 32 * 2];    // 2 KiB

    const int tid = threadIdx.x;
    const int bid = blockIdx.x;
    const int wp  = bid & 1;
    const int hg  = bid >> 1;                    // 0..127 (64 h-rows each)
    const int gidx = bid & 7;                    // 32 blocks/group (full grid)
    const int thr = load_threshold(thrp);

    const uint32_t* xPlane = xPP + (size_t)wp * 2 * F;
    uint32_t* pl0 = actPP + (size_t)(0 * 2 + wp) * 2 * H;
    uint32_t* pl1 = actPP + (size_t)(1 * 2 + wp) * 2 * H;
    uint32_t* pl2 = actPP + (size_t)(2 * 2 + wp) * 2 * H;
    const int*   idx2   = idxH;
    const float* signs2 = signsH;
    const int*   idx3   = idxH + (size_t)S * H * K;
    const float* signs3 = signsH + (size_t)S * H * K;

    // per-thread idx/signs element offset (identical for every layer)
    const int lane = tid & 63;
    const int ww   = tid >> 6;
    const size_t gb = ((size_t)(ww & 3) * H +
                       (size_t)hg * 64 + (ww >> 2) * 32 + (lane & 31)) * K +
                      (lane >> 5) * 16;

    // L1 idx/signs: issued immediately (overlap L1's own tab staging)
    ISRegs r1 = load_is(idx0, signs0, gb);
    layer_phase(xPlane, r1, pl0, thr, hg, tid, tab, fbuf);

    // L2 idx/signs: issued BEFORE bar1 -> completed by its drain while
    // waiting for the grid's slowest block (latency rides the barrier)
    ISRegs r2 = load_is(idx2, signs2, gb);
    grid_barrier(bar, 1, tid, gidx);
    layer_phase(pl0, r2, pl1, thr, hg, tid, tab, fbuf);

    ISRegs r3 = load_is(idx3, signs3, gb);       // rides bar2
    grid_barrier(bar, 2, tid, gidx);
    layer_phase(pl1, r3, pl2, thr, hg, tid, tab, fbuf);

    // final-phase geometry
    const int gw   = bid * 8 + ww;
    const int fb   = gw >> 4;                    // batch b
    const int hc   = gw & 15;                    // h-chunk (512 h)
    const int w32  = fb >> 5;
    const int fwp  = w32 >> 1;
    const int comp = w32 & 1;
    const int bit  = fb & 31;

    // mv[0]/mv[1]: planes grid-complete since bar1/bar2 -> ride bar3.
    uint32_t mv[L][8];
#pragma unroll
    for (int l = 0; l < 2; ++l) {
        const uint32_t* aT = actPP + (size_t)(l * 2 + fwp) * 2 * H + comp;
#pragma unroll
        for (int r = 0; r < 8; ++r)
            mv[l][r] = AG_LOAD(&aT[(size_t)(hc * 512 + r * 64 + lane) * 2]);
    }
    grid_barrier(bar, 3, tid, gidx);

    // mv[2] (needs bar3); its latency hides under the l=0/l=1 walks below
    {
        const uint32_t* aT = actPP + (size_t)(2 * 2 + fwp) * 2 * H + comp;
#pragma unroll
        for (int r = 0; r < 8; ++r)
            mv[2][r] = AG_LOAD(&aT[(size_t)(hc * 512 + r * 64 + lane) * 2]);
    }

    // ---- final: wave = (b, hc); batch-of-4 bit-walk, named scalars only ----
    {
        float acc0 = 0.0f, acc1 = 0.0f;
        const int c1 = 64 + lane;
        const bool c1v = (c1 < C);

#pragma unroll
        for (int l = 0; l < L; ++l) {
            const float* wl = wout + (size_t)l * H * C;
#pragma unroll
            for (int r = 0; r < 8; ++r) {
                const int hbase = hc * 512 + r * 64;
                uint64_t hm = __ballot((mv[l][r] >> bit) & 1u);
                while (hm) {
                    // __ffsll(0)-1 == -1, and hm &= hm-1 is a no-op at 0:
                    // slot extraction needs no conditionals.
                    const int sa = __ffsll((unsigned long long)hm) - 1; hm &= hm - 1;
                    const int sb = __ffsll((unsigned long long)hm) - 1; hm &= hm - 1;
                    const int sc = __ffsll((unsigned long long)hm) - 1; hm &= hm - 1;
                    const int sd = __ffsll((unsigned long long)hm) - 1; hm &= hm - 1;
                    float a0, a1 = 0.0f, b0 = 0.0f, b1 = 0.0f;
                    float c0 = 0.0f, c1f = 0.0f, d0 = 0.0f, d1 = 0.0f;
                    {   // sa is always valid inside the while
                        const float* w = wl + (size_t)(hbase + sa) * C;
                        a0 = w[lane];
                        if (c1v) a1 = w[c1];
                    }
                    if (sb >= 0) {
                        const float* w = wl + (size_t)(hbase + sb) * C;
                        b0 = w[lane];
                        if (c1v) b1 = w[c1];
                    }
                    if (sc >= 0) {
                        const float* w = wl + (size_t)(hbase + sc) * C;
                        c0 = w[lane];
                        if (c1v) c1f = w[c1];
                    }
                    if (sd >= 0) {
                        const float* w = wl + (size_t)(hbase + sd) * C;
                        d0 = w[lane];
                        if (c1v) d1 = w[c1];
                    }
                    acc0 += (a0 + b0) + (c0 + d0);
                    acc1 += (a1 + b1) + (c1f + d1);
                }
            }
        }
        atomicAdd(&out[fb * C + lane], acc0);
        if (c1v) atomicAdd(&out[fb * C + c1], acc1);
    }
}

// ---------------------------------------------------------------------------
extern "C" void kernel_launch(void* const* d_in, const int* in_sizes, int n_in,
                              void* d_out, int out_size, void* d_ws, size_t ws_size,
                              hipStream_t stream) {
    const float* x      = (const float*)d_in[0];   // (B,F)
    const float* signs0 = (const float*)d_in[1];   // (S,H,K)
    const float* signsH = (const float*)d_in[2];   // (L-1,S,H,K)
    const float* wout   = (const float*)d_in[3];   // (L,H,C)
    const int*   idx0   = (const int*)d_in[4];     // (S,H,K)
    const int*   idxH   = (const int*)d_in[5];     // (L-1,S,H,K)
    const int*   thr    = (const int*)d_in[6];     // scalar
    float* out = (float*)d_out;                    // (B,C)

    // Workspace: xPP [2][F] uint2 (128 KiB), actPP [L][2][H] uint2 (384 KiB),
    // barrier state (1024 u32, init-zeroed)
    uint32_t* xPP   = (uint32_t*)d_ws;
    uint32_t* actPP = xPP + (size_t)4 * F;
    uint32_t* bar   = actPP + (size_t)12 * H;
    uint2*    xPP2  = (uint2*)d_ws;

    init_pack_kernel<<<F / 32, 128, 0, stream>>>(x, xPP2, out, bar);
    fused_kernel<<<NBLK, NTHR, 0, stream>>>(xPP, idx0, signs0, idxH, signsH,
                                            wout, thr, actPP, out, bar);
}